// Round 6
// baseline (1193.322 us; speedup 1.0000x reference)
//
#include <hip/hip_runtime.h>

// Capsule routing, B=64 R=2048 C=32 O=32 I=16, 3 routing iters.
// u_hat never materialized; recomputed per pass. Logit telescoping:
// b1 = u.v1 ; b2 = u.(v1+v2) -> no [B,R,C] logit buffer.
//
// R6: R5 was bound by duplicated W traffic (FETCH 528 MB = ~4x W, 8 b-group
// blocks per rc on 8 different XCDs each refilling L2). Fixes:
// (1) W converted to fp16 once per call (wconv, 64 MB stream per upass),
//     cvt to fp32 regs once per r, inner FMA loop unchanged (fp16 W err
//     ~5e-4 rel -> v err ~1e-4 << 1.4e-2 threshold).
// (2) XCD swizzle: blocks sharing an rc get blockIdx == same (mod 8) ->
//     same XCD -> one L2 fill of the W chunk instead of 8.
// Kept from R5: x chunk in LDS (fp32), W ping-pong double-buffer,
// fully-unrolled b-loop (register-promoted state; R2-R4 spill lesson).

#define Bn 64
#define Rn 2048
#define Cn 32
#define On 32
#define In 16
#define RC 32            // r per upass block
#define NRC (Rn / RC)    // 64 r-chunks
#define GB 8             // b per upass block
#define NBG (Bn / GB)    // 8 b-groups

__device__ __forceinline__ float dot4(float4 a, float4 b) {
    return a.x * b.x + a.y * b.y + a.z * b.z + a.w * b.w;
}

// W fp32 [2048,32,32,16] -> fp16 same layout. 8 elements/thread, vectorized.
__global__ __launch_bounds__(256)
void wconv(const float* __restrict__ W, _Float16* __restrict__ Wh) {
    const size_t i = ((size_t)blockIdx.x * 256 + threadIdx.x) * 8;
    const float4 a = *(const float4*)(W + i);
    const float4 b = *(const float4*)(W + i + 4);
    union { _Float16 h[8]; uint4 u; } pk;
    pk.h[0] = (_Float16)a.x; pk.h[1] = (_Float16)a.y;
    pk.h[2] = (_Float16)a.z; pk.h[3] = (_Float16)a.w;
    pk.h[4] = (_Float16)b.x; pk.h[5] = (_Float16)b.y;
    pk.h[6] = (_Float16)b.z; pk.h[7] = (_Float16)b.w;
    *(uint4*)(Wh + i) = pk.u;
}

// s_part layout: [NRC][Bn][1024] floats; thread slot = float2 at index tid.
// Thread map (512 thr): w=tid>>6, lane=tid&63, c=lane&31, oh=lane>>5,
// o = 4*w + 2*oh + {0,1}.

template <int PHASE>
__global__ __launch_bounds__(512, 4)
void upass(const float* __restrict__ x, const _Float16* __restrict__ Wh,
           const float* __restrict__ vroute, float* __restrict__ s_part) {
    const int tid   = threadIdx.x;
    const int w     = tid >> 6;
    const int lane  = tid & 63;
    const int c     = lane & 31;
    const int oh    = lane >> 5;
    const int obase = (w << 2) + (oh << 1);

    // XCD swizzle: the 8 bg-blocks of one rc share blockIdx mod 8 -> same XCD.
    const int L  = blockIdx.x;
    const int bg = (L >> 3) & 7;
    const int rc = (L & 7) | ((L >> 6) << 3);   // [0,64)
    const int b0 = bg * GB;

    __shared__ float xs[GB][RC][In];   // 16 KB fp32, read-only after preload
    __shared__ float lds_l[2][256];    // logit o-partials, ping-pong on b&1

    // cooperative x preload: b = tid>>6 owns its 2 KB row (64 thr x 2 float4)
    {
        const int bb = tid >> 6, j = tid & 63;
        const float4* src = (const float4*)(x +
                            (size_t)(b0 + bb) * (Rn * In) + (size_t)rc * (RC * In));
        float4* dst = (float4*)&xs[bb][0][0];
        dst[j]      = src[j];
        dst[j + 64] = src[j + 64];
    }

    float2 vr[GB];
    if (PHASE > 0) {
#pragma unroll
        for (int b = 0; b < GB; ++b)
            vr[b] = *(const float2*)(vroute +
                     ((size_t)(b0 + b) * Cn + c) * On + obase);
    }

    float sacc0[GB], sacc1[GB];
#pragma unroll
    for (int b = 0; b < GB; ++b) { sacc0[b] = 0.f; sacc1[b] = 0.f; }

    __syncthreads();   // xs ready

    // W fp16: thread slice = [r, c, obase..+1, 0:16] = 32 halfs = 4 uint4.
    // per-r stride = Cn*On*In/8 = 2048 uint4.
    const uint4* Wb = (const uint4*)Wh +
                      ((size_t)((rc * RC) * Cn + c) * On + obase) * 2;

    auto cvtW = [&](const uint4 (&wr)[4], float4 (&wf)[8]) {
        const _Float16* h = (const _Float16*)&wr[0];
#pragma unroll
        for (int j = 0; j < 8; ++j)
            wf[j] = make_float4((float)h[4 * j], (float)h[4 * j + 1],
                                (float)h[4 * j + 2], (float)h[4 * j + 3]);
    };

    auto body = [&](int rr, const float4 (&wf)[8]) {
#pragma unroll
        for (int b = 0; b < GB; ++b) {
            const float4* xp = (const float4*)&xs[b][rr][0];   // broadcast
            const float4 x0 = xp[0], x1 = xp[1], x2 = xp[2], x3 = xp[3];
            const float u0 = dot4(wf[0], x0) + dot4(wf[1], x1) +
                             dot4(wf[2], x2) + dot4(wf[3], x3);
            const float u1 = dot4(wf[4], x0) + dot4(wf[5], x1) +
                             dot4(wf[6], x2) + dot4(wf[7], x3);

            float weight;
            if (PHASE == 0) {
                weight = 0.03125f;   // softmax(0) uniform = 1/32
            } else {
                float lp = u0 * vr[b].x + u1 * vr[b].y;  // 2 o's
                lp += __shfl_xor(lp, 32, 64);            // + oh partner
                if (lane < 32) lds_l[b & 1][w * 32 + c] = lp;
                __syncthreads();                          // 1 barrier/(rr,b)
                float l = 0.f;
#pragma unroll
                for (int k = 0; k < 8; ++k) l += lds_l[b & 1][k * 32 + c];
                // softmax over c (lanes 0..31 <-> c, dup upper half);
                // no max-subtract: |l| <~ 30 << 88 for N(0,1) inputs.
                const float e = __expf(l);
                float ssum = e;
#pragma unroll
                for (int d = 1; d < 32; d <<= 1)
                    ssum += __shfl_xor(ssum, d, 64);
                weight = e * __builtin_amdgcn_rcpf(ssum);
            }
            sacc0[b] = fmaf(weight, u0, sacc0[b]);
            sacc1[b] = fmaf(weight, u1, sacc1[b]);
        }
    };

    uint4 wa[4], wb[4];
    float4 wf[8];
#pragma unroll
    for (int j = 0; j < 4; ++j) wa[j] = Wb[j];

    for (int rr = 0; rr < RC; rr += 2) {
#pragma unroll
        for (int j = 0; j < 4; ++j) wb[j] = Wb[(size_t)(rr + 1) * 2048 + j];
        cvtW(wa, wf);
        body(rr, wf);
        if (rr + 2 < RC) {
#pragma unroll
            for (int j = 0; j < 4; ++j) wa[j] = Wb[(size_t)(rr + 2) * 2048 + j];
        }
        cvtW(wb, wf);
        body(rr + 1, wf);
    }

#pragma unroll
    for (int b = 0; b < GB; ++b)
        ((float2*)s_part)[((size_t)rc * Bn + (b0 + b)) * 512 + tid] =
            make_float2(sacc0[b], sacc1[b]);
}

// stage 1 reduce: 64 rc-partials -> 8 group-partials. grid (8, 64)
__global__ __launch_bounds__(256)
void reduce1(const float* __restrict__ s_part, float* __restrict__ s2) {
    const int g = blockIdx.x;   // [0,8)
    const int b = blockIdx.y;   // [0,64)
    const int t = threadIdx.x;
    float4 acc = make_float4(0.f, 0.f, 0.f, 0.f);
#pragma unroll
    for (int j = 0; j < 8; ++j) {
        float4 v = ((const float4*)s_part)[((size_t)(g * 8 + j) * Bn + b) * 256 + t];
        acc.x += v.x; acc.y += v.y; acc.z += v.z; acc.w += v.w;
    }
    ((float4*)s2)[((size_t)g * Bn + b) * 256 + t] = acc;
}

// stage 2: finish reduce, squash, write v ([b,c,o]); optional vsum = v+vprev.
// 512 threads, same (c, 2 o) slot map as upass.
__global__ __launch_bounds__(512)
void squash2(const float* __restrict__ s2, float scale,
             float* __restrict__ vout, const float* __restrict__ vprev,
             float* __restrict__ vsum_out) {
    const int b     = blockIdx.x;   // [0,64)
    const int t     = threadIdx.x;
    const int w     = t >> 6;
    const int lane  = t & 63;
    const int c     = lane & 31;
    const int oh    = lane >> 5;
    const int obase = (w << 2) + (oh << 1);
    __shared__ float lds_n[256];

    float2 acc = make_float2(0.f, 0.f);
#pragma unroll
    for (int g = 0; g < 8; ++g) {
        float2 v = ((const float2*)s2)[((size_t)g * Bn + b) * 512 + t];
        acc.x += v.x; acc.y += v.y;
    }
    acc.x *= scale; acc.y *= scale;

    float n2p = acc.x * acc.x + acc.y * acc.y;
    n2p += __shfl_xor(n2p, 32, 64);
    if (lane < 32) lds_n[w * 32 + c] = n2p;
    __syncthreads();
    float n2 = 0.f;
#pragma unroll
    for (int k = 0; k < 8; ++k) n2 += lds_n[k * 32 + c];
    const float norm = sqrtf(n2);
    const float f = (n2 / (1.f + n2)) / (norm + 1e-8f);

    float2 vv = make_float2(acc.x * f, acc.y * f);
    const size_t oidx = (size_t)b * 1024 + (size_t)c * 32 + obase;
    if (vout) *(float2*)(vout + oidx) = vv;
    if (vsum_out) {
        float2 vp = *(const float2*)(vprev + oidx);
        *(float2*)(vsum_out + oidx) = make_float2(vv.x + vp.x, vv.y + vp.y);
    }
}

extern "C" void kernel_launch(void* const* d_in, const int* in_sizes, int n_in,
                              void* d_out, int out_size, void* d_ws, size_t ws_size,
                              hipStream_t stream) {
    const float* x = (const float*)d_in[0];   // [64,2048,16]
    const float* W = (const float*)d_in[1];   // [2048,32,32,16]
    float* out = (float*)d_out;               // [64,32,32]

    char* ws = (char*)d_ws;
    _Float16* Wh  = (_Float16*)ws;                             // 64 MB
    float* s_part = (float*)(ws + (size_t)67108864);           // 16 MB
    float* s2     = (float*)(ws + (size_t)67108864 + 16777216);            // 2 MB
    float* v1     = (float*)(ws + (size_t)67108864 + 16777216 + 2097152);  // 256 KB
    float* v12    = (float*)(ws + (size_t)67108864 + 16777216 + 2097152 + 262144);

    const int ublocks = NBG * NRC;   // 512
    dim3 rg(8, Bn);                  // (8, 64)

    // W -> fp16 (33.5M elements, 8/thread)
    wconv<<<16384, 256, 0, stream>>>(W, Wh);

    // iter 1: uniform 1/32 applied INSIDE upass<0> (scale=1 in squash)
    upass<0><<<ublocks, 512, 0, stream>>>(x, Wh, nullptr, s_part);
    reduce1<<<rg, 256, 0, stream>>>(s_part, s2);
    squash2<<<Bn, 512, 0, stream>>>(s2, 1.0f, v1, nullptr, nullptr);

    // iter 2: logits = u.v1 ; keep only v12 = v1+v2
    upass<1><<<ublocks, 512, 0, stream>>>(x, Wh, v1, s_part);
    reduce1<<<rg, 256, 0, stream>>>(s_part, s2);
    squash2<<<Bn, 512, 0, stream>>>(s2, 1.f, nullptr, v1, v12);

    // iter 3: logits = u.(v1+v2) ; output v3
    upass<2><<<ublocks, 512, 0, stream>>>(x, Wh, v12, s_part);
    reduce1<<<rg, 256, 0, stream>>>(s_part, s2);
    squash2<<<Bn, 512, 0, stream>>>(s2, 1.f, out, nullptr, nullptr);
}

// Round 7
// 809.937 us; speedup vs baseline: 1.4734x; 1.4734x over previous
//
#include <hip/hip_runtime.h>

// Capsule routing, B=64 R=2048 C=32 O=32 I=16, 3 routing iters.
// u_hat never materialized; recomputed per pass. Logit telescoping:
// b1 = u.v1 ; b2 = u.(v1+v2) -> no [B,R,C] logit buffer.
//
// R7: R6's regression was __launch_bounds__(512,4) -> allocator clamped to
// 64 VGPR and spilled everything (WRITE 705 MB vs 16.4 MB algorithmic).
// EMPIRICAL RULE: at 512 threads this kernel needs bound=2 (104 VGPR, no
// spill). This round = R6 (fp16 W + XCD swizzle) with bound reverted to 2.
// Kept: x chunk in LDS, W ping-pong double-buffer, fully-unrolled b-loop
// (register-promoted per-b state; R2-R4 spill lesson).

#define Bn 64
#define Rn 2048
#define Cn 32
#define On 32
#define In 16
#define RC 32            // r per upass block
#define NRC (Rn / RC)    // 64 r-chunks
#define GB 8             // b per upass block
#define NBG (Bn / GB)    // 8 b-groups

__device__ __forceinline__ float dot4(float4 a, float4 b) {
    return a.x * b.x + a.y * b.y + a.z * b.z + a.w * b.w;
}

// W fp32 [2048,32,32,16] -> fp16 same layout. 8 elements/thread, vectorized.
__global__ __launch_bounds__(256)
void wconv(const float* __restrict__ W, _Float16* __restrict__ Wh) {
    const size_t i = ((size_t)blockIdx.x * 256 + threadIdx.x) * 8;
    const float4 a = *(const float4*)(W + i);
    const float4 b = *(const float4*)(W + i + 4);
    union { _Float16 h[8]; uint4 u; } pk;
    pk.h[0] = (_Float16)a.x; pk.h[1] = (_Float16)a.y;
    pk.h[2] = (_Float16)a.z; pk.h[3] = (_Float16)a.w;
    pk.h[4] = (_Float16)b.x; pk.h[5] = (_Float16)b.y;
    pk.h[6] = (_Float16)b.z; pk.h[7] = (_Float16)b.w;
    *(uint4*)(Wh + i) = pk.u;
}

// s_part layout: [NRC][Bn][1024] floats; thread slot = float2 at index tid.
// Thread map (512 thr): w=tid>>6, lane=tid&63, c=lane&31, oh=lane>>5,
// o = 4*w + 2*oh + {0,1}.

template <int PHASE>
__global__ __launch_bounds__(512, 2)   // bound=2: do NOT raise (R6 lesson)
void upass(const float* __restrict__ x, const _Float16* __restrict__ Wh,
           const float* __restrict__ vroute, float* __restrict__ s_part) {
    const int tid   = threadIdx.x;
    const int w     = tid >> 6;
    const int lane  = tid & 63;
    const int c     = lane & 31;
    const int oh    = lane >> 5;
    const int obase = (w << 2) + (oh << 1);

    // XCD swizzle: the 8 bg-blocks of one rc share blockIdx mod 8 -> same XCD.
    const int L  = blockIdx.x;
    const int bg = (L >> 3) & 7;
    const int rc = (L & 7) | ((L >> 6) << 3);   // [0,64)
    const int b0 = bg * GB;

    __shared__ float xs[GB][RC][In];   // 16 KB fp32, read-only after preload
    __shared__ float lds_l[2][256];    // logit o-partials, ping-pong on b&1

    // cooperative x preload: b = tid>>6 owns its 2 KB row (64 thr x 2 float4)
    {
        const int bb = tid >> 6, j = tid & 63;
        const float4* src = (const float4*)(x +
                            (size_t)(b0 + bb) * (Rn * In) + (size_t)rc * (RC * In));
        float4* dst = (float4*)&xs[bb][0][0];
        dst[j]      = src[j];
        dst[j + 64] = src[j + 64];
    }

    float2 vr[GB];
    if (PHASE > 0) {
#pragma unroll
        for (int b = 0; b < GB; ++b)
            vr[b] = *(const float2*)(vroute +
                     ((size_t)(b0 + b) * Cn + c) * On + obase);
    }

    float sacc0[GB], sacc1[GB];
#pragma unroll
    for (int b = 0; b < GB; ++b) { sacc0[b] = 0.f; sacc1[b] = 0.f; }

    __syncthreads();   // xs ready

    // W fp16: thread slice = [r, c, obase..+1, 0:16] = 32 halfs = 4 uint4.
    // per-r stride = Cn*On*In/8 = 2048 uint4.
    const uint4* Wb = (const uint4*)Wh +
                      ((size_t)((rc * RC) * Cn + c) * On + obase) * 2;

    auto cvtW = [&](const uint4 (&wr)[4], float4 (&wf)[8]) {
        const _Float16* h = (const _Float16*)&wr[0];
#pragma unroll
        for (int j = 0; j < 8; ++j)
            wf[j] = make_float4((float)h[4 * j], (float)h[4 * j + 1],
                                (float)h[4 * j + 2], (float)h[4 * j + 3]);
    };

    auto body = [&](int rr, const float4 (&wf)[8]) {
#pragma unroll
        for (int b = 0; b < GB; ++b) {
            const float4* xp = (const float4*)&xs[b][rr][0];   // broadcast
            const float4 x0 = xp[0], x1 = xp[1], x2 = xp[2], x3 = xp[3];
            const float u0 = dot4(wf[0], x0) + dot4(wf[1], x1) +
                             dot4(wf[2], x2) + dot4(wf[3], x3);
            const float u1 = dot4(wf[4], x0) + dot4(wf[5], x1) +
                             dot4(wf[6], x2) + dot4(wf[7], x3);

            float weight;
            if (PHASE == 0) {
                weight = 0.03125f;   // softmax(0) uniform = 1/32
            } else {
                float lp = u0 * vr[b].x + u1 * vr[b].y;  // 2 o's
                lp += __shfl_xor(lp, 32, 64);            // + oh partner
                if (lane < 32) lds_l[b & 1][w * 32 + c] = lp;
                __syncthreads();                          // 1 barrier/(rr,b)
                float l = 0.f;
#pragma unroll
                for (int k = 0; k < 8; ++k) l += lds_l[b & 1][k * 32 + c];
                // softmax over c (lanes 0..31 <-> c, dup upper half);
                // no max-subtract: |l| <~ 30 << 88 for N(0,1) inputs.
                const float e = __expf(l);
                float ssum = e;
#pragma unroll
                for (int d = 1; d < 32; d <<= 1)
                    ssum += __shfl_xor(ssum, d, 64);
                weight = e * __builtin_amdgcn_rcpf(ssum);
            }
            sacc0[b] = fmaf(weight, u0, sacc0[b]);
            sacc1[b] = fmaf(weight, u1, sacc1[b]);
        }
    };

    uint4 wa[4], wb[4];
    float4 wf[8];
#pragma unroll
    for (int j = 0; j < 4; ++j) wa[j] = Wb[j];

    for (int rr = 0; rr < RC; rr += 2) {
#pragma unroll
        for (int j = 0; j < 4; ++j) wb[j] = Wb[(size_t)(rr + 1) * 2048 + j];
        cvtW(wa, wf);
        body(rr, wf);
        if (rr + 2 < RC) {
#pragma unroll
            for (int j = 0; j < 4; ++j) wa[j] = Wb[(size_t)(rr + 2) * 2048 + j];
        }
        cvtW(wb, wf);
        body(rr + 1, wf);
    }

#pragma unroll
    for (int b = 0; b < GB; ++b)
        ((float2*)s_part)[((size_t)rc * Bn + (b0 + b)) * 512 + tid] =
            make_float2(sacc0[b], sacc1[b]);
}

// stage 1 reduce: 64 rc-partials -> 8 group-partials. grid (8, 64)
__global__ __launch_bounds__(256)
void reduce1(const float* __restrict__ s_part, float* __restrict__ s2) {
    const int g = blockIdx.x;   // [0,8)
    const int b = blockIdx.y;   // [0,64)
    const int t = threadIdx.x;
    float4 acc = make_float4(0.f, 0.f, 0.f, 0.f);
#pragma unroll
    for (int j = 0; j < 8; ++j) {
        float4 v = ((const float4*)s_part)[((size_t)(g * 8 + j) * Bn + b) * 256 + t];
        acc.x += v.x; acc.y += v.y; acc.z += v.z; acc.w += v.w;
    }
    ((float4*)s2)[((size_t)g * Bn + b) * 256 + t] = acc;
}

// stage 2: finish reduce, squash, write v ([b,c,o]); optional vsum = v+vprev.
// 512 threads, same (c, 2 o) slot map as upass.
__global__ __launch_bounds__(512)
void squash2(const float* __restrict__ s2, float scale,
             float* __restrict__ vout, const float* __restrict__ vprev,
             float* __restrict__ vsum_out) {
    const int b     = blockIdx.x;   // [0,64)
    const int t     = threadIdx.x;
    const int w     = t >> 6;
    const int lane  = t & 63;
    const int c     = lane & 31;
    const int oh    = lane >> 5;
    const int obase = (w << 2) + (oh << 1);
    __shared__ float lds_n[256];

    float2 acc = make_float2(0.f, 0.f);
#pragma unroll
    for (int g = 0; g < 8; ++g) {
        float2 v = ((const float2*)s2)[((size_t)g * Bn + b) * 512 + t];
        acc.x += v.x; acc.y += v.y;
    }
    acc.x *= scale; acc.y *= scale;

    float n2p = acc.x * acc.x + acc.y * acc.y;
    n2p += __shfl_xor(n2p, 32, 64);
    if (lane < 32) lds_n[w * 32 + c] = n2p;
    __syncthreads();
    float n2 = 0.f;
#pragma unroll
    for (int k = 0; k < 8; ++k) n2 += lds_n[k * 32 + c];
    const float norm = sqrtf(n2);
    const float f = (n2 / (1.f + n2)) / (norm + 1e-8f);

    float2 vv = make_float2(acc.x * f, acc.y * f);
    const size_t oidx = (size_t)b * 1024 + (size_t)c * 32 + obase;
    if (vout) *(float2*)(vout + oidx) = vv;
    if (vsum_out) {
        float2 vp = *(const float2*)(vprev + oidx);
        *(float2*)(vsum_out + oidx) = make_float2(vv.x + vp.x, vv.y + vp.y);
    }
}

extern "C" void kernel_launch(void* const* d_in, const int* in_sizes, int n_in,
                              void* d_out, int out_size, void* d_ws, size_t ws_size,
                              hipStream_t stream) {
    const float* x = (const float*)d_in[0];   // [64,2048,16]
    const float* W = (const float*)d_in[1];   // [2048,32,32,16]
    float* out = (float*)d_out;               // [64,32,32]

    char* ws = (char*)d_ws;
    _Float16* Wh  = (_Float16*)ws;                             // 64 MB
    float* s_part = (float*)(ws + (size_t)67108864);           // 16 MB
    float* s2     = (float*)(ws + (size_t)67108864 + 16777216);            // 2 MB
    float* v1     = (float*)(ws + (size_t)67108864 + 16777216 + 2097152);  // 256 KB
    float* v12    = (float*)(ws + (size_t)67108864 + 16777216 + 2097152 + 262144);

    const int ublocks = NBG * NRC;   // 512
    dim3 rg(8, Bn);                  // (8, 64)

    // W -> fp16 (33.5M elements, 8/thread)
    wconv<<<16384, 256, 0, stream>>>(W, Wh);

    // iter 1: uniform 1/32 applied INSIDE upass<0> (scale=1 in squash)
    upass<0><<<ublocks, 512, 0, stream>>>(x, Wh, nullptr, s_part);
    reduce1<<<rg, 256, 0, stream>>>(s_part, s2);
    squash2<<<Bn, 512, 0, stream>>>(s2, 1.0f, v1, nullptr, nullptr);

    // iter 2: logits = u.v1 ; keep only v12 = v1+v2
    upass<1><<<ublocks, 512, 0, stream>>>(x, Wh, v1, s_part);
    reduce1<<<rg, 256, 0, stream>>>(s_part, s2);
    squash2<<<Bn, 512, 0, stream>>>(s2, 1.f, nullptr, v1, v12);

    // iter 3: logits = u.(v1+v2) ; output v3
    upass<2><<<ublocks, 512, 0, stream>>>(x, Wh, v12, s_part);
    reduce1<<<rg, 256, 0, stream>>>(s_part, s2);
    squash2<<<Bn, 512, 0, stream>>>(s2, 1.f, out, nullptr, nullptr);
}

// Round 9
// 721.107 us; speedup vs baseline: 1.6548x; 1.1232x over previous
//
#include <hip/hip_runtime.h>

// Capsule routing, B=64 R=2048 C=32 O=32 I=16, 3 routing iters.
// u_hat never materialized; recomputed per pass. Logit telescoping:
// b1 = u.v1 ; b2 = u.(v1+v2) -> no [B,R,C] logit buffer.
//
// R9 = R8 with the W-slice size bug fixed: per-thread slice is 2 o x 16 i
// = 32 halfs = 64 B = FOUR uint4 (R8 loaded two -> read past the array ->
// NaN). Structure: x converted to fp16 at preload (xs 8 KB, 2 ds_read_b128
// per body), W packed fp16 in regs (no cvt in loop), u0/u1 via
// v_dot2_f32_f16. Kept: fp16 W stream (FETCH 39 MB, L3-resident), XCD
// swizzle, ping-pong W prefetch, fully-unrolled b-loop,
// __launch_bounds__(512,2) (R6 lesson: bound=4 clamps to 64 VGPR, spills).

#define Bn 64
#define Rn 2048
#define Cn 32
#define On 32
#define In 16
#define RC 32            // r per upass block
#define NRC (Rn / RC)    // 64 r-chunks
#define GB 8             // b per upass block
#define NBG (Bn / GB)    // 8 b-groups

typedef _Float16 half2v __attribute__((ext_vector_type(2)));

#if defined(__has_builtin)
#if __has_builtin(__builtin_amdgcn_fdot2)
#define FDOT2(a, b, c) __builtin_amdgcn_fdot2((a), (b), (c), false)
#endif
#endif
#ifndef FDOT2
#define FDOT2(a, b, c) fmaf((float)(a).x, (float)(b).x, \
                        fmaf((float)(a).y, (float)(b).y, (c)))
#endif

// W fp32 [2048,32,32,16] -> fp16 same layout. 8 elements/thread, vectorized.
__global__ __launch_bounds__(256)
void wconv(const float* __restrict__ W, _Float16* __restrict__ Wh) {
    const size_t i = ((size_t)blockIdx.x * 256 + threadIdx.x) * 8;
    const float4 a = *(const float4*)(W + i);
    const float4 b = *(const float4*)(W + i + 4);
    union { _Float16 h[8]; uint4 u; } pk;
    pk.h[0] = (_Float16)a.x; pk.h[1] = (_Float16)a.y;
    pk.h[2] = (_Float16)a.z; pk.h[3] = (_Float16)a.w;
    pk.h[4] = (_Float16)b.x; pk.h[5] = (_Float16)b.y;
    pk.h[6] = (_Float16)b.z; pk.h[7] = (_Float16)b.w;
    *(uint4*)(Wh + i) = pk.u;
}

// s_part layout: [NRC][Bn][1024] floats; thread slot = float2 at index tid.
// Thread map (512 thr): w=tid>>6, lane=tid&63, c=lane&31, oh=lane>>5,
// o = 4*w + 2*oh + {0,1}.

template <int PHASE>
__global__ __launch_bounds__(512, 2)   // bound=2: do NOT raise (R6 lesson)
void upass(const float* __restrict__ x, const _Float16* __restrict__ Wh,
           const float* __restrict__ vroute, float* __restrict__ s_part) {
    const int tid   = threadIdx.x;
    const int w     = tid >> 6;
    const int lane  = tid & 63;
    const int c     = lane & 31;
    const int oh    = lane >> 5;
    const int obase = (w << 2) + (oh << 1);

    // XCD swizzle: the 8 bg-blocks of one rc share blockIdx mod 8 -> same XCD.
    const int L  = blockIdx.x;
    const int bg = (L >> 3) & 7;
    const int rc = (L & 7) | ((L >> 6) << 3);   // [0,64)
    const int b0 = bg * GB;

    __shared__ __attribute__((aligned(16))) _Float16 xs[GB * RC * In]; // 8 KB
    __shared__ float lds_l[2][256];    // logit o-partials, ping-pong on b&1

    // cooperative x preload + fp32->fp16: b = tid>>6 owns its row chunk
    {
        const int bb = tid >> 6, j = tid & 63;
        const float4* src = (const float4*)(x +
                            (size_t)(b0 + bb) * (Rn * In) + (size_t)rc * (RC * In));
        _Float16* dsth = xs + bb * (RC * In);
        const float4 a0 = src[j];
        const float4 a1 = src[j + 64];
        union { _Float16 h[4]; uint2 u; } p0, p1;
        p0.h[0] = (_Float16)a0.x; p0.h[1] = (_Float16)a0.y;
        p0.h[2] = (_Float16)a0.z; p0.h[3] = (_Float16)a0.w;
        p1.h[0] = (_Float16)a1.x; p1.h[1] = (_Float16)a1.y;
        p1.h[2] = (_Float16)a1.z; p1.h[3] = (_Float16)a1.w;
        *(uint2*)(dsth + 4 * j)        = p0.u;
        *(uint2*)(dsth + 4 * (j + 64)) = p1.u;
    }

    float2 vr[GB];
    if (PHASE > 0) {
#pragma unroll
        for (int b = 0; b < GB; ++b)
            vr[b] = *(const float2*)(vroute +
                     ((size_t)(b0 + b) * Cn + c) * On + obase);
    }

    float sacc0[GB], sacc1[GB];
#pragma unroll
    for (int b = 0; b < GB; ++b) { sacc0[b] = 0.f; sacc1[b] = 0.f; }

    __syncthreads();   // xs ready

    // W fp16: thread slice = [r, c, obase..+1, 0:16] = 32 halfs = 4 uint4.
    // per-r stride = Cn*On*In/8 = 2048 uint4.
    const uint4* Wb = (const uint4*)Wh +
                      ((size_t)((rc * RC) * Cn + c) * On + obase) * 2;

    auto body = [&](int rr, const uint4 (&wst)[4]) {
        const half2v* wh = (const half2v*)&wst[0];   // [0..7]=o0, [8..15]=o1
#pragma unroll
        for (int b = 0; b < GB; ++b) {
            uint4 xr[2];
            xr[0] = *(const uint4*)(xs + (b * RC + rr) * In);
            xr[1] = *(const uint4*)(xs + (b * RC + rr) * In + 8);
            const half2v* xh = (const half2v*)&xr[0];  // 8 half2
            float u0 = 0.f, u1 = 0.f;
#pragma unroll
            for (int j = 0; j < 8; ++j) {
                u0 = FDOT2(wh[j],     xh[j], u0);
                u1 = FDOT2(wh[8 + j], xh[j], u1);
            }

            float weight;
            if (PHASE == 0) {
                weight = 0.03125f;   // softmax(0) uniform = 1/32
            } else {
                float lp = u0 * vr[b].x + u1 * vr[b].y;  // 2 o's
                lp += __shfl_xor(lp, 32, 64);            // + oh partner
                if (lane < 32) lds_l[b & 1][w * 32 + c] = lp;
                __syncthreads();                          // 1 barrier/(rr,b)
                float l = 0.f;
#pragma unroll
                for (int k = 0; k < 8; ++k) l += lds_l[b & 1][k * 32 + c];
                // softmax over c (lanes 0..31 <-> c, dup upper half);
                // no max-subtract: |l| <~ 30 << 88 for N(0,1) inputs.
                const float e = __expf(l);
                float ssum = e;
#pragma unroll
                for (int d = 1; d < 32; d <<= 1)
                    ssum += __shfl_xor(ssum, d, 64);
                weight = e * __builtin_amdgcn_rcpf(ssum);
            }
            sacc0[b] = fmaf(weight, u0, sacc0[b]);
            sacc1[b] = fmaf(weight, u1, sacc1[b]);
        }
    };

    uint4 wa[4], wb[4];
#pragma unroll
    for (int j = 0; j < 4; ++j) wa[j] = Wb[j];

    for (int rr = 0; rr < RC; rr += 2) {
#pragma unroll
        for (int j = 0; j < 4; ++j) wb[j] = Wb[(size_t)(rr + 1) * 2048 + j];
        body(rr, wa);
        if (rr + 2 < RC) {
#pragma unroll
            for (int j = 0; j < 4; ++j) wa[j] = Wb[(size_t)(rr + 2) * 2048 + j];
        }
        body(rr + 1, wb);
    }

#pragma unroll
    for (int b = 0; b < GB; ++b)
        ((float2*)s_part)[((size_t)rc * Bn + (b0 + b)) * 512 + tid] =
            make_float2(sacc0[b], sacc1[b]);
}

// stage 1 reduce: 64 rc-partials -> 8 group-partials. grid (8, 64)
__global__ __launch_bounds__(256)
void reduce1(const float* __restrict__ s_part, float* __restrict__ s2) {
    const int g = blockIdx.x;   // [0,8)
    const int b = blockIdx.y;   // [0,64)
    const int t = threadIdx.x;
    float4 acc = make_float4(0.f, 0.f, 0.f, 0.f);
#pragma unroll
    for (int j = 0; j < 8; ++j) {
        float4 v = ((const float4*)s_part)[((size_t)(g * 8 + j) * Bn + b) * 256 + t];
        acc.x += v.x; acc.y += v.y; acc.z += v.z; acc.w += v.w;
    }
    ((float4*)s2)[((size_t)g * Bn + b) * 256 + t] = acc;
}

// stage 2: finish reduce, squash, write v ([b,c,o]); optional vsum = v+vprev.
// 512 threads, same (c, 2 o) slot map as upass.
__global__ __launch_bounds__(512)
void squash2(const float* __restrict__ s2, float scale,
             float* __restrict__ vout, const float* __restrict__ vprev,
             float* __restrict__ vsum_out) {
    const int b     = blockIdx.x;   // [0,64)
    const int t     = threadIdx.x;
    const int w     = t >> 6;
    const int lane  = t & 63;
    const int c     = lane & 31;
    const int oh    = lane >> 5;
    const int obase = (w << 2) + (oh << 1);
    __shared__ float lds_n[256];

    float2 acc = make_float2(0.f, 0.f);
#pragma unroll
    for (int g = 0; g < 8; ++g) {
        float2 v = ((const float2*)s2)[((size_t)g * Bn + b) * 512 + t];
        acc.x += v.x; acc.y += v.y;
    }
    acc.x *= scale; acc.y *= scale;

    float n2p = acc.x * acc.x + acc.y * acc.y;
    n2p += __shfl_xor(n2p, 32, 64);
    if (lane < 32) lds_n[w * 32 + c] = n2p;
    __syncthreads();
    float n2 = 0.f;
#pragma unroll
    for (int k = 0; k < 8; ++k) n2 += lds_n[k * 32 + c];
    const float norm = sqrtf(n2);
    const float f = (n2 / (1.f + n2)) / (norm + 1e-8f);

    float2 vv = make_float2(acc.x * f, acc.y * f);
    const size_t oidx = (size_t)b * 1024 + (size_t)c * 32 + obase;
    if (vout) *(float2*)(vout + oidx) = vv;
    if (vsum_out) {
        float2 vp = *(const float2*)(vprev + oidx);
        *(float2*)(vsum_out + oidx) = make_float2(vv.x + vp.x, vv.y + vp.y);
    }
}

extern "C" void kernel_launch(void* const* d_in, const int* in_sizes, int n_in,
                              void* d_out, int out_size, void* d_ws, size_t ws_size,
                              hipStream_t stream) {
    const float* x = (const float*)d_in[0];   // [64,2048,16]
    const float* W = (const float*)d_in[1];   // [2048,32,32,16]
    float* out = (float*)d_out;               // [64,32,32]

    char* ws = (char*)d_ws;
    _Float16* Wh  = (_Float16*)ws;                             // 64 MB
    float* s_part = (float*)(ws + (size_t)67108864);           // 16 MB
    float* s2     = (float*)(ws + (size_t)67108864 + 16777216);            // 2 MB
    float* v1     = (float*)(ws + (size_t)67108864 + 16777216 + 2097152);  // 256 KB
    float* v12    = (float*)(ws + (size_t)67108864 + 16777216 + 2097152 + 262144);

    const int ublocks = NBG * NRC;   // 512
    dim3 rg(8, Bn);                  // (8, 64)

    // W -> fp16 (33.5M elements, 8/thread)
    wconv<<<16384, 256, 0, stream>>>(W, Wh);

    // iter 1: uniform 1/32 applied INSIDE upass<0> (scale=1 in squash)
    upass<0><<<ublocks, 512, 0, stream>>>(x, Wh, nullptr, s_part);
    reduce1<<<rg, 256, 0, stream>>>(s_part, s2);
    squash2<<<Bn, 512, 0, stream>>>(s2, 1.0f, v1, nullptr, nullptr);

    // iter 2: logits = u.v1 ; keep only v12 = v1+v2
    upass<1><<<ublocks, 512, 0, stream>>>(x, Wh, v1, s_part);
    reduce1<<<rg, 256, 0, stream>>>(s_part, s2);
    squash2<<<Bn, 512, 0, stream>>>(s2, 1.f, nullptr, v1, v12);

    // iter 3: logits = u.(v1+v2) ; output v3
    upass<2><<<ublocks, 512, 0, stream>>>(x, Wh, v12, s_part);
    reduce1<<<rg, 256, 0, stream>>>(s_part, s2);
    squash2<<<Bn, 512, 0, stream>>>(s2, 1.f, out, nullptr, nullptr);
}